// Round 8
// baseline (580.858 us; speedup 1.0000x reference)
//
#include <hip/hip_runtime.h>
#include <math.h>

#define N_NODES 100000
#define N_EDGES 1600000
#define D 128
#define NCLASS 10
#define NLAYERS 3
#define BN_EPS 1e-5f

#define LDA 136        // padded LDS row stride in bf16 elems
#define BUCKET_SH 7    // 128 nodes per bucket
#define NBUK 782       // ceil(100000/128)
#define NBLK 256       // partition blocks (== scan chunk size -> psums[i] = bucket i base)
#define CHUNK 6250     // N_EDGES / NBLK (exact)
#define SCAN_BLKS NBUK

typedef __attribute__((ext_vector_type(8))) short bf16x8;
typedef __attribute__((ext_vector_type(4))) float f32x4;
typedef __attribute__((ext_vector_type(2))) uint u32x2;
typedef __attribute__((ext_vector_type(4))) uint u32x4;

__device__ __forceinline__ ushort f2b(float x) {          // RNE fp32 -> bf16
    uint u = __float_as_uint(x);
    return (ushort)((u + 0x7fffu + ((u >> 16) & 1u)) >> 16);
}
__device__ __forceinline__ float b2f(uint u) {            // bf16 bits -> fp32 (exact)
    return __uint_as_float(u << 16);
}
__device__ __forceinline__ uint pack2(float a, float b) {
    return (uint)f2b(a) | ((uint)f2b(b) << 16);
}

// ================= CSR build: radix partition, no global atomics =================
__global__ __launch_bounds__(256) void k_hist(const int* __restrict__ dst,
                                              int* __restrict__ hist) {
    __shared__ int lh[NBUK];
    int t = threadIdx.x, b = blockIdx.x;
    for (int i = t; i < NBUK; i += 256) lh[i] = 0;
    __syncthreads();
    int e0 = b * CHUNK;
    for (int e = e0 + t; e < e0 + CHUNK; e += 256)
        atomicAdd(&lh[dst[e] >> BUCKET_SH], 1);
    __syncthreads();
    for (int i = t; i < NBUK; i += 256) hist[i * NBLK + b] = lh[i];
}

__global__ __launch_bounds__(256) void k_scan1(int* __restrict__ hist, int* __restrict__ psums) {
    __shared__ int sh[256];
    int t = threadIdx.x;
    int i = blockIdx.x * 256 + t;
    int v = hist[i];
    sh[t] = v; __syncthreads();
    for (int off = 1; off < 256; off <<= 1) {
        int a = (t >= off) ? sh[t - off] : 0;
        __syncthreads();
        sh[t] += a;
        __syncthreads();
    }
    hist[i] = sh[t] - v;
    if (t == 255) psums[blockIdx.x] = sh[255];
}

__global__ __launch_bounds__(1024) void k_scan2(int* __restrict__ psums) {
    __shared__ int sh[1024];
    int t = threadIdx.x;
    int v = (t < SCAN_BLKS) ? psums[t] : 0;
    sh[t] = v; __syncthreads();
    for (int off = 1; off < 1024; off <<= 1) {
        int a = (t >= off) ? sh[t - off] : 0;
        __syncthreads();
        sh[t] += a;
        __syncthreads();
    }
    if (t < SCAN_BLKS) psums[t] = sh[t] - v;
}

__global__ __launch_bounds__(256) void k_partition(const int* __restrict__ src,
                                                   const int* __restrict__ dst,
                                                   const int* __restrict__ hist,
                                                   const int* __restrict__ psums,
                                                   uint* __restrict__ tmp) {
    __shared__ int lcur[NBUK];
    int t = threadIdx.x, b = blockIdx.x;
    for (int i = t; i < NBUK; i += 256) lcur[i] = hist[i * NBLK + b] + psums[i];
    __syncthreads();
    int e0 = b * CHUNK;
    for (int e = e0 + t; e < e0 + CHUNK; e += 256) {
        int d = dst[e];
        int bk = d >> BUCKET_SH;
        int pos = atomicAdd(&lcur[bk], 1);
        tmp[pos] = (uint)src[e] | ((uint)(d & ((1 << BUCKET_SH) - 1)) << 17);
    }
}

__global__ __launch_bounds__(256) void k_bucket_fill(const uint* __restrict__ tmp,
                                                     const int* __restrict__ psums,
                                                     int* __restrict__ row_ptr,
                                                     int* __restrict__ csr) {
    __shared__ int hist[128], inc[128], cur[128];
    int b = blockIdx.x, t = threadIdx.x;
    int base = psums[b];
    int end  = (b + 1 < NBUK) ? psums[b + 1] : N_EDGES;
    int nb = end - base;
    int lo = b << BUCKET_SH;
    const uint* bt = tmp + base;

    if (t < 128) hist[t] = 0;
    __syncthreads();
    for (int i = t; i < nb; i += 256)
        atomicAdd(&hist[bt[i] >> 17], 1);
    __syncthreads();
    if (t < 128) inc[t] = hist[t];
    __syncthreads();
    for (int offs = 1; offs < 128; offs <<= 1) {
        int a = (t < 128 && t >= offs) ? inc[t - offs] : 0;
        __syncthreads();
        if (t < 128) inc[t] += a;
        __syncthreads();
    }
    if (t < 128) {
        int node = lo + t;
        if (node < N_NODES) row_ptr[node] = base + inc[t] - hist[t];
        cur[t] = 0;
    }
    if (b == NBUK - 1 && t == 0) row_ptr[N_NODES] = base + nb;
    __syncthreads();
    for (int i = t; i < nb; i += 256) {
        uint u = bt[i];
        int dl = u >> 17;
        int s = (int)(u & 0x1ffffu);
        int p = atomicAdd(&cur[dl], 1);
        csr[base + (inc[dl] - hist[dl]) + p] = s;
    }
}

// ================= fp32 -> bf16: x and all weights =================
__global__ void k_conv(const float* __restrict__ x, const float* __restrict__ W1,
                       const float* __restrict__ W2, const float* __restrict__ l1W,
                       ushort* __restrict__ hbf, ushort* __restrict__ wbf) {
    int i = blockIdx.x * 256 + threadIdx.x;
    const int n4x = N_NODES * D / 4;               // 3,200,000
    if (i < n4x) {
        float4 v = ((const float4*)x)[i];
        u32x2 u;
        u.x = pack2(v.x, v.y);
        u.y = pack2(v.z, v.w);
        ((u32x2*)hbf)[i] = u;
    } else {
        int k = i - n4x;                           // float4 index into weights
        const float* srcp;
        ushort* dstp;
        if (k < 12288)      { srcp = W1 + k * 4;            dstp = wbf + k * 4; }
        else if (k < 24576) { srcp = W2 + (k - 12288) * 4;  dstp = wbf + 49152 + (k - 12288) * 4; }
        else if (k < 28672) { srcp = l1W + (k - 24576) * 4; dstp = wbf + 98304 + (k - 24576) * 4; }
        else return;
        float4 v = *(const float4*)srcp;
        ushort4 u;
        u.x = f2b(v.x); u.y = f2b(v.y); u.z = f2b(v.z); u.w = f2b(v.w);
        *(ushort4*)dstp = u;
    }
}

// ================= aggregation v2: 8B lanes, 2 rows/load, 16 rows in flight =========
__global__ __launch_bounds__(256) void k_aggregate(const ushort* __restrict__ hbf,
                                                   const int* __restrict__ row_ptr,
                                                   const int* __restrict__ csr,
                                                   ushort* __restrict__ outbf) {
    int node = blockIdx.x * 4 + (threadIdx.x >> 6);
    int lane = threadIdx.x & 63;
    int sub = lane >> 5;           // which edge of the pair
    int c = lane & 31;             // 8B column group (4 bf16)
    const u32x2* hp = (const u32x2*)hbf;
    u32x2 sv = hp[(size_t)node * 32 + c];
    float a0 = 0.f, a1 = 0.f, a2 = 0.f, a3 = 0.f;
    int e0 = row_ptr[node], e1 = row_ptr[node + 1];
    int e = e0;
    for (; e + 15 < e1; e += 16) {
        u32x2 v0 = __builtin_nontemporal_load(&hp[(size_t)csr[e      + sub] * 32 + c]);
        u32x2 v1 = __builtin_nontemporal_load(&hp[(size_t)csr[e + 2  + sub] * 32 + c]);
        u32x2 v2 = __builtin_nontemporal_load(&hp[(size_t)csr[e + 4  + sub] * 32 + c]);
        u32x2 v3 = __builtin_nontemporal_load(&hp[(size_t)csr[e + 6  + sub] * 32 + c]);
        u32x2 v4 = __builtin_nontemporal_load(&hp[(size_t)csr[e + 8  + sub] * 32 + c]);
        u32x2 v5 = __builtin_nontemporal_load(&hp[(size_t)csr[e + 10 + sub] * 32 + c]);
        u32x2 v6 = __builtin_nontemporal_load(&hp[(size_t)csr[e + 12 + sub] * 32 + c]);
        u32x2 v7 = __builtin_nontemporal_load(&hp[(size_t)csr[e + 14 + sub] * 32 + c]);
        a0 += b2f(v0.x & 0xffffu); a1 += b2f(v0.x >> 16); a2 += b2f(v0.y & 0xffffu); a3 += b2f(v0.y >> 16);
        a0 += b2f(v1.x & 0xffffu); a1 += b2f(v1.x >> 16); a2 += b2f(v1.y & 0xffffu); a3 += b2f(v1.y >> 16);
        a0 += b2f(v2.x & 0xffffu); a1 += b2f(v2.x >> 16); a2 += b2f(v2.y & 0xffffu); a3 += b2f(v2.y >> 16);
        a0 += b2f(v3.x & 0xffffu); a1 += b2f(v3.x >> 16); a2 += b2f(v3.y & 0xffffu); a3 += b2f(v3.y >> 16);
        a0 += b2f(v4.x & 0xffffu); a1 += b2f(v4.x >> 16); a2 += b2f(v4.y & 0xffffu); a3 += b2f(v4.y >> 16);
        a0 += b2f(v5.x & 0xffffu); a1 += b2f(v5.x >> 16); a2 += b2f(v5.y & 0xffffu); a3 += b2f(v5.y >> 16);
        a0 += b2f(v6.x & 0xffffu); a1 += b2f(v6.x >> 16); a2 += b2f(v6.y & 0xffffu); a3 += b2f(v6.y >> 16);
        a0 += b2f(v7.x & 0xffffu); a1 += b2f(v7.x >> 16); a2 += b2f(v7.y & 0xffffu); a3 += b2f(v7.y >> 16);
    }
    for (; e + 1 < e1; e += 2) {
        u32x2 v = __builtin_nontemporal_load(&hp[(size_t)csr[e + sub] * 32 + c]);
        a0 += b2f(v.x & 0xffffu); a1 += b2f(v.x >> 16);
        a2 += b2f(v.y & 0xffffu); a3 += b2f(v.y >> 16);
    }
    if (e < e1 && sub == 0) {      // odd tail: only first half contributes
        u32x2 v = __builtin_nontemporal_load(&hp[(size_t)csr[e] * 32 + c]);
        a0 += b2f(v.x & 0xffffu); a1 += b2f(v.x >> 16);
        a2 += b2f(v.y & 0xffffu); a3 += b2f(v.y >> 16);
    }
    // combine the two half-wave partials
    a0 += __shfl_xor(a0, 32, 64);
    a1 += __shfl_xor(a1, 32, 64);
    a2 += __shfl_xor(a2, 32, 64);
    a3 += __shfl_xor(a3, 32, 64);
    // add self
    a0 += b2f(sv.x & 0xffffu); a1 += b2f(sv.x >> 16);
    a2 += b2f(sv.y & 0xffffu); a3 += b2f(sv.y >> 16);
    if (sub == 0) {
        u32x2 o;
        o.x = pack2(a0, a1);
        o.y = pack2(a2, a3);
        __builtin_nontemporal_store(o, (u32x2*)outbf + (size_t)node * 32 + c);
    }
}

// ================= MFMA GEMM: A from LDS, W(bf16) direct from global =================
// PRE: 0 = copy bf16 A; 2 = relu(a*scale[k]+shift[k]).  POST: 1 = relu.
// STATS: fused column sum/sumsq (fp32, pre-rounding), LDS-reduced.
template <int PRE, int POST, int STATS>
__global__ __launch_bounds__(256, 4) void k_gemm(const ushort* __restrict__ inA,
                                                 const ushort* __restrict__ Wbf,
                                                 const float* __restrict__ bias,
                                                 const float* __restrict__ scale,
                                                 const float* __restrict__ shift,
                                                 ushort* __restrict__ outp,
                                                 float* __restrict__ gsum,
                                                 float* __restrict__ gsq,
                                                 int nrows) {
    __shared__ ushort sA[128 * LDA];
    __shared__ float sbias[128];
    __shared__ float lsum[128], lsq[128];

    int t = threadIdx.x;
    int r0 = blockIdx.x * 128;

    if (t < 128) {
        sbias[t] = bias[t];
        lsum[t] = 0.f; lsq[t] = 0.f;
    }

    for (int idx = t; idx < 128 * 16; idx += 256) {
        int r = idx >> 4, c8 = (idx & 15) << 3;
        int rr = r0 + r;
        u32x4 v = (u32x4){0u, 0u, 0u, 0u};
        if (rr < nrows) v = __builtin_nontemporal_load((const u32x4*)(inA + (size_t)rr * 128 + c8));
        if (PRE == 2) {
            float f0 = b2f(v.x & 0xffffu), f1 = b2f(v.x >> 16);
            float f2 = b2f(v.y & 0xffffu), f3 = b2f(v.y >> 16);
            float f4 = b2f(v.z & 0xffffu), f5 = b2f(v.z >> 16);
            float f6 = b2f(v.w & 0xffffu), f7 = b2f(v.w >> 16);
            float4 sc0 = *(const float4*)(scale + c8);
            float4 sc1 = *(const float4*)(scale + c8 + 4);
            float4 sf0 = *(const float4*)(shift + c8);
            float4 sf1 = *(const float4*)(shift + c8 + 4);
            f0 = fmaxf(fmaf(f0, sc0.x, sf0.x), 0.f);
            f1 = fmaxf(fmaf(f1, sc0.y, sf0.y), 0.f);
            f2 = fmaxf(fmaf(f2, sc0.z, sf0.z), 0.f);
            f3 = fmaxf(fmaf(f3, sc0.w, sf0.w), 0.f);
            f4 = fmaxf(fmaf(f4, sc1.x, sf1.x), 0.f);
            f5 = fmaxf(fmaf(f5, sc1.y, sf1.y), 0.f);
            f6 = fmaxf(fmaf(f6, sc1.z, sf1.z), 0.f);
            f7 = fmaxf(fmaf(f7, sc1.w, sf1.w), 0.f);
            v.x = pack2(f0, f1); v.y = pack2(f2, f3);
            v.z = pack2(f4, f5); v.w = pack2(f6, f7);
        }
        *(u32x4*)&sA[r * LDA + c8] = v;
    }
    __syncthreads();

    int lane = t & 63, wid = t >> 6;
    int rl = lane & 15, g = lane >> 4;
    int wr = wid >> 1, wc = wid & 1;

    f32x4 acc[4][4];
#pragma unroll
    for (int i = 0; i < 4; ++i)
#pragma unroll
        for (int j = 0; j < 4; ++j) acc[i][j] = (f32x4){0.f, 0.f, 0.f, 0.f};

#pragma unroll
    for (int ks = 0; ks < 4; ++ks) {
        int koff = ks * 32 + g * 8;
        bf16x8 a[4], b[4];
#pragma unroll
        for (int ni = 0; ni < 4; ++ni)
            b[ni] = *(const bf16x8*)&Wbf[(size_t)(wc * 64 + ni * 16 + rl) * 128 + koff];
#pragma unroll
        for (int mi = 0; mi < 4; ++mi)
            a[mi] = *(const bf16x8*)&sA[(wr * 64 + mi * 16 + rl) * LDA + koff];
#pragma unroll
        for (int mi = 0; mi < 4; ++mi)
#pragma unroll
            for (int ni = 0; ni < 4; ++ni)
                acc[mi][ni] = __builtin_amdgcn_mfma_f32_16x16x32_bf16(a[mi], b[ni], acc[mi][ni], 0, 0, 0);
    }

    float bn[4], ssum[4], ssq[4];
#pragma unroll
    for (int ni = 0; ni < 4; ++ni) {
        bn[ni] = sbias[wc * 64 + ni * 16 + rl];
        ssum[ni] = 0.f; ssq[ni] = 0.f;
    }

#pragma unroll
    for (int mi = 0; mi < 4; ++mi) {
        int orow = r0 + wr * 64 + mi * 16 + g * 4;
#pragma unroll
        for (int j = 0; j < 4; ++j) {
            int row = orow + j;
            if (row < nrows) {
#pragma unroll
                for (int ni = 0; ni < 4; ++ni) {
                    int ocol = wc * 64 + ni * 16 + rl;
                    float o = acc[mi][ni][j] + bn[ni];
                    if (STATS) { ssum[ni] += o; ssq[ni] += o * o; }
                    if (POST) o = fmaxf(o, 0.f);
                    outp[(size_t)row * 128 + ocol] = f2b(o);
                }
            }
        }
    }

    if (STATS) {
#pragma unroll
        for (int ni = 0; ni < 4; ++ni) {
            float s = ssum[ni], q = ssq[ni];
            s += __shfl_xor(s, 16, 64); q += __shfl_xor(q, 16, 64);
            s += __shfl_xor(s, 32, 64); q += __shfl_xor(q, 32, 64);
            if (g == 0) {
                int col = wc * 64 + ni * 16 + rl;
                atomicAdd(&lsum[col], s);
                atomicAdd(&lsq[col], q);
            }
        }
        __syncthreads();
        if (t < 128) {
            atomicAdd(&gsum[t], lsum[t]);
            atomicAdd(&gsq[t], lsq[t]);
        }
    }
}

// ================= BN finalize (+ self-reset of accumulators) =================
__global__ void k_bnfin(float* __restrict__ gsum, float* __restrict__ gsq,
                        const float* __restrict__ gamma, const float* __restrict__ beta,
                        float* __restrict__ scale, float* __restrict__ shift) {
    int d = threadIdx.x;
    float s = gsum[d], q = gsq[d];
    float mu = s * (1.f / N_NODES);
    float var = q * (1.f / N_NODES) - mu * mu;
    float rstd = rsqrtf(var + BN_EPS);
    float sc = rstd * gamma[d];
    scale[d] = sc;
    shift[d] = beta[d] - mu * sc;
    gsum[d] = 0.f;
    gsq[d] = 0.f;
}

// ================= fused head: out = sigmoid(relu(h@l1W.T+l1b) @ l2W.T + l2b) ========
__global__ __launch_bounds__(256, 3) void k_head(const ushort* __restrict__ hbf,
                                                 const ushort* __restrict__ l1bf,
                                                 const float* __restrict__ b1f,
                                                 const float* __restrict__ W2,
                                                 const float* __restrict__ b2f_,
                                                 float* __restrict__ out) {
    __shared__ ushort sA[128 * LDA];          // h tile, later reused as z^T tile
    __shared__ float sbias[128];
    __shared__ float w2s[NCLASS * 128];
    __shared__ float b2s[NCLASS];

    int t = threadIdx.x;
    int r0 = blockIdx.x * 128;

    if (t < 128) sbias[t] = b1f[t];
    for (int idx = t; idx < (NCLASS * 128) / 4; idx += 256)
        *(float4*)&w2s[idx * 4] = *(const float4*)(W2 + idx * 4);
    if (t < NCLASS) b2s[t] = b2f_[t];

    for (int idx = t; idx < 128 * 16; idx += 256) {
        int r = idx >> 4, c8 = (idx & 15) << 3;
        int rr = r0 + r;
        u32x4 v = (u32x4){0u, 0u, 0u, 0u};
        if (rr < N_NODES) v = __builtin_nontemporal_load((const u32x4*)(hbf + (size_t)rr * 128 + c8));
        *(u32x4*)&sA[r * LDA + c8] = v;
    }
    __syncthreads();

    int lane = t & 63, wid = t >> 6;
    int rl = lane & 15, g = lane >> 4;
    int wr = wid >> 1, wc = wid & 1;

    f32x4 acc[4][4];
#pragma unroll
    for (int i = 0; i < 4; ++i)
#pragma unroll
        for (int j = 0; j < 4; ++j) acc[i][j] = (f32x4){0.f, 0.f, 0.f, 0.f};

#pragma unroll
    for (int ks = 0; ks < 4; ++ks) {
        int koff = ks * 32 + g * 8;
        bf16x8 a[4], b[4];
#pragma unroll
        for (int ni = 0; ni < 4; ++ni)
            b[ni] = *(const bf16x8*)&l1bf[(size_t)(wc * 64 + ni * 16 + rl) * 128 + koff];
#pragma unroll
        for (int mi = 0; mi < 4; ++mi)
            a[mi] = *(const bf16x8*)&sA[(wr * 64 + mi * 16 + rl) * LDA + koff];
#pragma unroll
        for (int mi = 0; mi < 4; ++mi)
#pragma unroll
            for (int ni = 0; ni < 4; ++ni)
                acc[mi][ni] = __builtin_amdgcn_mfma_f32_16x16x32_bf16(a[mi], b[ni], acc[mi][ni], 0, 0, 0);
    }

    __syncthreads();   // all waves done reading sA -> safe to overwrite with z^T

    float bn[4];
#pragma unroll
    for (int ni = 0; ni < 4; ++ni) bn[ni] = sbias[wc * 64 + ni * 16 + rl];
#pragma unroll
    for (int mi = 0; mi < 4; ++mi) {
        int rowl = wr * 64 + mi * 16 + g * 4;
#pragma unroll
        for (int j = 0; j < 4; ++j) {
#pragma unroll
            for (int ni = 0; ni < 4; ++ni) {
                int ocol = wc * 64 + ni * 16 + rl;
                float o = fmaxf(acc[mi][ni][j] + bn[ni], 0.f);
                sA[ocol * LDA + rowl + j] = f2b(o);   // z^T: [col][row]
            }
        }
    }
    __syncthreads();

    int row = t & 127, ch = t >> 7;
    float acc2[5] = {0.f, 0.f, 0.f, 0.f, 0.f};
    const float* w2p = &w2s[ch * 5 * 128];
#pragma unroll 4
    for (int k = 0; k < 128; ++k) {
        float v = b2f(sA[k * LDA + row]);
#pragma unroll
        for (int c = 0; c < 5; ++c)
            acc2[c] = fmaf(v, w2p[c * 128 + k], acc2[c]);
    }
    int rr = r0 + row;
    if (rr < N_NODES) {
#pragma unroll
        for (int c = 0; c < 5; ++c) {
            float z = acc2[c] + b2s[ch * 5 + c];
            out[(size_t)rr * NCLASS + ch * 5 + c] = 1.f / (1.f + expf(-z));
        }
    }
}

// ================= launcher =================
extern "C" void kernel_launch(void* const* d_in, const int* in_sizes, int n_in,
                              void* d_out, int out_size, void* d_ws, size_t ws_size,
                              hipStream_t stream) {
    const float* x     = (const float*)d_in[0];
    const int*   ei    = (const int*)d_in[1];
    const float* W1    = (const float*)d_in[2];
    const float* b1    = (const float*)d_in[3];
    const float* gamma = (const float*)d_in[4];
    const float* beta  = (const float*)d_in[5];
    const float* W2    = (const float*)d_in[6];
    const float* b2    = (const float*)d_in[7];
    const float* l1W   = (const float*)d_in[8];
    const float* l1b   = (const float*)d_in[9];
    const float* l2W   = (const float*)d_in[10];
    const float* l2b   = (const float*)d_in[11];
    float* out = (float*)d_out;

    char* w = (char*)d_ws;
    ushort* hbf    = (ushort*)(w);                   // 25,600,000 B
    ushort* zbf    = (ushort*)(w + 25600000);        // 25,600,000 B
    ushort* aggout = (ushort*)(w + 51200000);        // 25,600,000 B
    int*   row_ptr = (int*)   (w + 76800000);        // 400,004 B (reserve 400,640)
    int*   csr     = (int*)   (w + 77200640);        // 6,400,000 B
    uint*  tmp     = (uint*)  (w + 83600640);        // 6,400,000 B
    int*   hist    = (int*)   (w + 90000640);        // 800,768 (reserve 801,280)
    int*   psums   = (int*)   (w + 90801920);        // reserve 4,096
    float* gsum    = (float*) (w + 90806016);        // 512 floats (2048 B)
    float* gsq     = gsum + 128;
    float* scale   = gsum + 256;
    float* shift   = gsum + 384;
    ushort* wbf    = (ushort*)(w + 90808064);        // 114,688 ushorts = 229,376 B
    ushort* w1bf   = wbf;                            // [3][128][128]
    ushort* w2bf   = wbf + 49152;                    // [3][128][128]
    ushort* l1bf   = wbf + 98304;                    // [128][128]

    const int* src = ei;
    const int* dst = ei + N_EDGES;

    const int GEMM_NB = (N_NODES + 127) / 128;       // 782

    (void)hipMemsetAsync(gsum, 0, 256 * sizeof(float), stream);

    // ---- CSR build (radix partition, zero global atomics) ----
    k_hist<<<NBLK, 256, 0, stream>>>(dst, hist);
    k_scan1<<<SCAN_BLKS, 256, 0, stream>>>(hist, psums);
    k_scan2<<<1, 1024, 0, stream>>>(psums);
    k_partition<<<NBLK, 256, 0, stream>>>(src, dst, hist, psums, tmp);
    k_bucket_fill<<<NBUK, 256, 0, stream>>>(tmp, psums, row_ptr, csr);

    // ---- x + weights -> bf16 ----
    const int CONV_NB = (N_NODES * D / 4 + 28672 + 255) / 256;
    k_conv<<<CONV_NB, 256, 0, stream>>>(x, W1, W2, l1W, hbf, wbf);

    // ---- 3 GIN layers ----
    for (int l = 0; l < NLAYERS; ++l) {
        k_aggregate<<<N_NODES / 4, 256, 0, stream>>>(hbf, row_ptr, csr, aggout);
        // z = (h+agg) @ W1.T + b1  (bf16 out) + fused column stats
        k_gemm<0, 0, 1><<<GEMM_NB, 256, 0, stream>>>(aggout, w1bf + l * D * D, b1 + l * D,
                                                     nullptr, nullptr, zbf, gsum, gsq, N_NODES);
        k_bnfin<<<1, 128, 0, stream>>>(gsum, gsq, gamma + l * D, beta + l * D, scale, shift);
        // h' = relu( relu(BN(z)) @ W2.T + b2 )
        k_gemm<2, 1, 0><<<GEMM_NB, 256, 0, stream>>>(zbf, w2bf + l * D * D, b2 + l * D,
                                                     scale, shift, hbf, nullptr, nullptr, N_NODES);
    }

    // ---- fused head ----
    k_head<<<GEMM_NB, 256, 0, stream>>>(hbf, l1bf, l1b, l2W, l2b, out);
}

// Round 9
// 477.299 us; speedup vs baseline: 1.2170x; 1.2170x over previous
//
#include <hip/hip_runtime.h>
#include <math.h>

#define N_NODES 100000
#define N_EDGES 1600000
#define D 128
#define NCLASS 10
#define NLAYERS 3
#define BN_EPS 1e-5f

#define LDA 136        // padded LDS row stride in bf16 elems
#define BUCKET_SH 7    // 128 nodes per bucket
#define NBUK 782       // ceil(100000/128)
#define NBLK 256       // partition blocks (== scan chunk size -> psums[i] = bucket i base)
#define CHUNK 6250     // N_EDGES / NBLK (exact)
#define SCAN_BLKS NBUK

typedef __attribute__((ext_vector_type(8))) short bf16x8;
typedef __attribute__((ext_vector_type(4))) float f32x4;
typedef __attribute__((ext_vector_type(4))) uint u32x4;

__device__ __forceinline__ ushort f2b(float x) {          // RNE fp32 -> bf16
    uint u = __float_as_uint(x);
    return (ushort)((u + 0x7fffu + ((u >> 16) & 1u)) >> 16);
}
__device__ __forceinline__ float b2f(uint u) {            // bf16 bits -> fp32 (exact)
    return __uint_as_float(u << 16);
}
__device__ __forceinline__ uint pack2(float a, float b) {
    return (uint)f2b(a) | ((uint)f2b(b) << 16);
}

// ================= CSR build: radix partition, no global atomics =================
__global__ __launch_bounds__(256) void k_hist(const int* __restrict__ dst,
                                              int* __restrict__ hist) {
    __shared__ int lh[NBUK];
    int t = threadIdx.x, b = blockIdx.x;
    for (int i = t; i < NBUK; i += 256) lh[i] = 0;
    __syncthreads();
    int e0 = b * CHUNK;
    for (int e = e0 + t; e < e0 + CHUNK; e += 256)
        atomicAdd(&lh[dst[e] >> BUCKET_SH], 1);
    __syncthreads();
    for (int i = t; i < NBUK; i += 256) hist[i * NBLK + b] = lh[i];
}

__global__ __launch_bounds__(256) void k_scan1(int* __restrict__ hist, int* __restrict__ psums) {
    __shared__ int sh[256];
    int t = threadIdx.x;
    int i = blockIdx.x * 256 + t;
    int v = hist[i];
    sh[t] = v; __syncthreads();
    for (int off = 1; off < 256; off <<= 1) {
        int a = (t >= off) ? sh[t - off] : 0;
        __syncthreads();
        sh[t] += a;
        __syncthreads();
    }
    hist[i] = sh[t] - v;
    if (t == 255) psums[blockIdx.x] = sh[255];
}

__global__ __launch_bounds__(1024) void k_scan2(int* __restrict__ psums) {
    __shared__ int sh[1024];
    int t = threadIdx.x;
    int v = (t < SCAN_BLKS) ? psums[t] : 0;
    sh[t] = v; __syncthreads();
    for (int off = 1; off < 1024; off <<= 1) {
        int a = (t >= off) ? sh[t - off] : 0;
        __syncthreads();
        sh[t] += a;
        __syncthreads();
    }
    if (t < SCAN_BLKS) psums[t] = sh[t] - v;
}

__global__ __launch_bounds__(256) void k_partition(const int* __restrict__ src,
                                                   const int* __restrict__ dst,
                                                   const int* __restrict__ hist,
                                                   const int* __restrict__ psums,
                                                   uint* __restrict__ tmp) {
    __shared__ int lcur[NBUK];
    int t = threadIdx.x, b = blockIdx.x;
    for (int i = t; i < NBUK; i += 256) lcur[i] = hist[i * NBLK + b] + psums[i];
    __syncthreads();
    int e0 = b * CHUNK;
    for (int e = e0 + t; e < e0 + CHUNK; e += 256) {
        int d = dst[e];
        int bk = d >> BUCKET_SH;
        int pos = atomicAdd(&lcur[bk], 1);
        tmp[pos] = (uint)src[e] | ((uint)(d & ((1 << BUCKET_SH) - 1)) << 17);
    }
}

__global__ __launch_bounds__(256) void k_bucket_fill(const uint* __restrict__ tmp,
                                                     const int* __restrict__ psums,
                                                     int* __restrict__ row_ptr,
                                                     int* __restrict__ csr) {
    __shared__ int hist[128], inc[128], cur[128];
    int b = blockIdx.x, t = threadIdx.x;
    int base = psums[b];
    int end  = (b + 1 < NBUK) ? psums[b + 1] : N_EDGES;
    int nb = end - base;
    int lo = b << BUCKET_SH;
    const uint* bt = tmp + base;

    if (t < 128) hist[t] = 0;
    __syncthreads();
    for (int i = t; i < nb; i += 256)
        atomicAdd(&hist[bt[i] >> 17], 1);
    __syncthreads();
    if (t < 128) inc[t] = hist[t];
    __syncthreads();
    for (int offs = 1; offs < 128; offs <<= 1) {
        int a = (t < 128 && t >= offs) ? inc[t - offs] : 0;
        __syncthreads();
        if (t < 128) inc[t] += a;
        __syncthreads();
    }
    if (t < 128) {
        int node = lo + t;
        if (node < N_NODES) row_ptr[node] = base + inc[t] - hist[t];
        cur[t] = 0;
    }
    if (b == NBUK - 1 && t == 0) row_ptr[N_NODES] = base + nb;
    __syncthreads();
    for (int i = t; i < nb; i += 256) {
        uint u = bt[i];
        int dl = u >> 17;
        int s = (int)(u & 0x1ffffu);
        int p = atomicAdd(&cur[dl], 1);
        csr[base + (inc[dl] - hist[dl]) + p] = s;
    }
}

// ================= fp32 -> bf16: x and all weights =================
__global__ void k_conv(const float* __restrict__ x, const float* __restrict__ W1,
                       const float* __restrict__ W2, const float* __restrict__ l1W,
                       ushort* __restrict__ hbf, ushort* __restrict__ wbf) {
    int i = blockIdx.x * 256 + threadIdx.x;
    const int n4x = N_NODES * D / 4;               // 3,200,000
    if (i < n4x) {
        float4 v = ((const float4*)x)[i];
        uint2 u;
        u.x = pack2(v.x, v.y);
        u.y = pack2(v.z, v.w);
        ((uint2*)hbf)[i] = u;
    } else {
        int k = i - n4x;                           // float4 index into weights
        const float* srcp;
        ushort* dstp;
        if (k < 12288)      { srcp = W1 + k * 4;            dstp = wbf + k * 4; }
        else if (k < 24576) { srcp = W2 + (k - 12288) * 4;  dstp = wbf + 49152 + (k - 12288) * 4; }
        else if (k < 28672) { srcp = l1W + (k - 24576) * 4; dstp = wbf + 98304 + (k - 24576) * 4; }
        else return;
        float4 v = *(const float4*)srcp;
        ushort4 u;
        u.x = f2b(v.x); u.y = f2b(v.y); u.z = f2b(v.z); u.w = f2b(v.w);
        *(ushort4*)dstp = u;
    }
}

// ================= aggregation (round-6 proven version: 4B lanes, 1 row/instr) =========
__global__ __launch_bounds__(256) void k_aggregate(const ushort* __restrict__ hbf,
                                                   const int* __restrict__ row_ptr,
                                                   const int* __restrict__ csr,
                                                   ushort* __restrict__ outbf) {
    int node = blockIdx.x * 4 + (threadIdx.x >> 6);
    int lane = threadIdx.x & 63;
    const uint* hp = (const uint*)hbf;
    uint self = hp[(size_t)node * 64 + lane];
    float ax = b2f(self & 0xffffu), ay = b2f(self >> 16);
    int e0 = row_ptr[node], e1 = row_ptr[node + 1];
    int e = e0;
    for (; e + 7 < e1; e += 8) {
        uint v0 = hp[(size_t)csr[e]     * 64 + lane];
        uint v1 = hp[(size_t)csr[e + 1] * 64 + lane];
        uint v2 = hp[(size_t)csr[e + 2] * 64 + lane];
        uint v3 = hp[(size_t)csr[e + 3] * 64 + lane];
        uint v4 = hp[(size_t)csr[e + 4] * 64 + lane];
        uint v5 = hp[(size_t)csr[e + 5] * 64 + lane];
        uint v6 = hp[(size_t)csr[e + 6] * 64 + lane];
        uint v7 = hp[(size_t)csr[e + 7] * 64 + lane];
        ax += b2f(v0 & 0xffffu); ay += b2f(v0 >> 16);
        ax += b2f(v1 & 0xffffu); ay += b2f(v1 >> 16);
        ax += b2f(v2 & 0xffffu); ay += b2f(v2 >> 16);
        ax += b2f(v3 & 0xffffu); ay += b2f(v3 >> 16);
        ax += b2f(v4 & 0xffffu); ay += b2f(v4 >> 16);
        ax += b2f(v5 & 0xffffu); ay += b2f(v5 >> 16);
        ax += b2f(v6 & 0xffffu); ay += b2f(v6 >> 16);
        ax += b2f(v7 & 0xffffu); ay += b2f(v7 >> 16);
    }
    for (; e < e1; ++e) {
        uint v = hp[(size_t)csr[e] * 64 + lane];
        ax += b2f(v & 0xffffu); ay += b2f(v >> 16);
    }
    __builtin_nontemporal_store(pack2(ax, ay), (uint*)outbf + (size_t)node * 64 + lane);
}

// ================= MFMA GEMM: A from LDS, W(bf16) direct from global =================
// PRE: 0 = copy bf16 A; 2 = relu(a*scale[k]+shift[k]).  POST: 1 = relu.
// STATS: fused column sum/sumsq (fp32, pre-rounding), LDS-reduced.
template <int PRE, int POST, int STATS>
__global__ __launch_bounds__(256, 4) void k_gemm(const ushort* __restrict__ inA,
                                                 const ushort* __restrict__ Wbf,
                                                 const float* __restrict__ bias,
                                                 const float* __restrict__ scale,
                                                 const float* __restrict__ shift,
                                                 ushort* __restrict__ outp,
                                                 float* __restrict__ gsum,
                                                 float* __restrict__ gsq,
                                                 int nrows) {
    __shared__ ushort sA[128 * LDA];
    __shared__ float sbias[128];
    __shared__ float lsum[128], lsq[128];

    int t = threadIdx.x;
    int r0 = blockIdx.x * 128;

    if (t < 128) {
        sbias[t] = bias[t];
        lsum[t] = 0.f; lsq[t] = 0.f;
    }

    for (int idx = t; idx < 128 * 16; idx += 256) {
        int r = idx >> 4, c8 = (idx & 15) << 3;
        int rr = r0 + r;
        u32x4 v = (u32x4){0u, 0u, 0u, 0u};
        if (rr < nrows) v = __builtin_nontemporal_load((const u32x4*)(inA + (size_t)rr * 128 + c8));
        if (PRE == 2) {
            float f0 = b2f(v.x & 0xffffu), f1 = b2f(v.x >> 16);
            float f2 = b2f(v.y & 0xffffu), f3 = b2f(v.y >> 16);
            float f4 = b2f(v.z & 0xffffu), f5 = b2f(v.z >> 16);
            float f6 = b2f(v.w & 0xffffu), f7 = b2f(v.w >> 16);
            float4 sc0 = *(const float4*)(scale + c8);
            float4 sc1 = *(const float4*)(scale + c8 + 4);
            float4 sf0 = *(const float4*)(shift + c8);
            float4 sf1 = *(const float4*)(shift + c8 + 4);
            f0 = fmaxf(fmaf(f0, sc0.x, sf0.x), 0.f);
            f1 = fmaxf(fmaf(f1, sc0.y, sf0.y), 0.f);
            f2 = fmaxf(fmaf(f2, sc0.z, sf0.z), 0.f);
            f3 = fmaxf(fmaf(f3, sc0.w, sf0.w), 0.f);
            f4 = fmaxf(fmaf(f4, sc1.x, sf1.x), 0.f);
            f5 = fmaxf(fmaf(f5, sc1.y, sf1.y), 0.f);
            f6 = fmaxf(fmaf(f6, sc1.z, sf1.z), 0.f);
            f7 = fmaxf(fmaf(f7, sc1.w, sf1.w), 0.f);
            v.x = pack2(f0, f1); v.y = pack2(f2, f3);
            v.z = pack2(f4, f5); v.w = pack2(f6, f7);
        }
        *(u32x4*)&sA[r * LDA + c8] = v;
    }
    __syncthreads();

    int lane = t & 63, wid = t >> 6;
    int rl = lane & 15, g = lane >> 4;
    int wr = wid >> 1, wc = wid & 1;

    f32x4 acc[4][4];
#pragma unroll
    for (int i = 0; i < 4; ++i)
#pragma unroll
        for (int j = 0; j < 4; ++j) acc[i][j] = (f32x4){0.f, 0.f, 0.f, 0.f};

#pragma unroll
    for (int ks = 0; ks < 4; ++ks) {
        int koff = ks * 32 + g * 8;
        bf16x8 a[4], b[4];
#pragma unroll
        for (int ni = 0; ni < 4; ++ni)
            b[ni] = *(const bf16x8*)&Wbf[(size_t)(wc * 64 + ni * 16 + rl) * 128 + koff];
#pragma unroll
        for (int mi = 0; mi < 4; ++mi)
            a[mi] = *(const bf16x8*)&sA[(wr * 64 + mi * 16 + rl) * LDA + koff];
#pragma unroll
        for (int mi = 0; mi < 4; ++mi)
#pragma unroll
            for (int ni = 0; ni < 4; ++ni)
                acc[mi][ni] = __builtin_amdgcn_mfma_f32_16x16x32_bf16(a[mi], b[ni], acc[mi][ni], 0, 0, 0);
    }

    float bn[4], ssum[4], ssq[4];
#pragma unroll
    for (int ni = 0; ni < 4; ++ni) {
        bn[ni] = sbias[wc * 64 + ni * 16 + rl];
        ssum[ni] = 0.f; ssq[ni] = 0.f;
    }

#pragma unroll
    for (int mi = 0; mi < 4; ++mi) {
        int orow = r0 + wr * 64 + mi * 16 + g * 4;
#pragma unroll
        for (int j = 0; j < 4; ++j) {
            int row = orow + j;
            if (row < nrows) {
#pragma unroll
                for (int ni = 0; ni < 4; ++ni) {
                    int ocol = wc * 64 + ni * 16 + rl;
                    float o = acc[mi][ni][j] + bn[ni];
                    if (STATS) { ssum[ni] += o; ssq[ni] += o * o; }
                    if (POST) o = fmaxf(o, 0.f);
                    outp[(size_t)row * 128 + ocol] = f2b(o);
                }
            }
        }
    }

    if (STATS) {
#pragma unroll
        for (int ni = 0; ni < 4; ++ni) {
            float s = ssum[ni], q = ssq[ni];
            s += __shfl_xor(s, 16, 64); q += __shfl_xor(q, 16, 64);
            s += __shfl_xor(s, 32, 64); q += __shfl_xor(q, 32, 64);
            if (g == 0) {
                int col = wc * 64 + ni * 16 + rl;
                atomicAdd(&lsum[col], s);
                atomicAdd(&lsq[col], q);
            }
        }
        __syncthreads();
        if (t < 128) {
            atomicAdd(&gsum[t], lsum[t]);
            atomicAdd(&gsq[t], lsq[t]);
        }
    }
}

// ================= BN finalize (+ self-reset of accumulators) =================
__global__ void k_bnfin(float* __restrict__ gsum, float* __restrict__ gsq,
                        const float* __restrict__ gamma, const float* __restrict__ beta,
                        float* __restrict__ scale, float* __restrict__ shift) {
    int d = threadIdx.x;
    float s = gsum[d], q = gsq[d];
    float mu = s * (1.f / N_NODES);
    float var = q * (1.f / N_NODES) - mu * mu;
    float rstd = rsqrtf(var + BN_EPS);
    float sc = rstd * gamma[d];
    scale[d] = sc;
    shift[d] = beta[d] - mu * sc;
    gsum[d] = 0.f;
    gsq[d] = 0.f;
}

// ================= fused head: out = sigmoid(relu(h@l1W.T+l1b) @ l2W.T + l2b) ========
__global__ __launch_bounds__(256, 3) void k_head(const ushort* __restrict__ hbf,
                                                 const ushort* __restrict__ l1bf,
                                                 const float* __restrict__ b1f,
                                                 const float* __restrict__ W2,
                                                 const float* __restrict__ b2f_,
                                                 float* __restrict__ out) {
    __shared__ ushort sA[128 * LDA];          // h tile, later reused as z^T tile
    __shared__ float sbias[128];
    __shared__ float w2s[NCLASS * 128];
    __shared__ float b2s[NCLASS];

    int t = threadIdx.x;
    int r0 = blockIdx.x * 128;

    if (t < 128) sbias[t] = b1f[t];
    for (int idx = t; idx < (NCLASS * 128) / 4; idx += 256)
        *(float4*)&w2s[idx * 4] = *(const float4*)(W2 + idx * 4);
    if (t < NCLASS) b2s[t] = b2f_[t];

    for (int idx = t; idx < 128 * 16; idx += 256) {
        int r = idx >> 4, c8 = (idx & 15) << 3;
        int rr = r0 + r;
        u32x4 v = (u32x4){0u, 0u, 0u, 0u};
        if (rr < N_NODES) v = __builtin_nontemporal_load((const u32x4*)(hbf + (size_t)rr * 128 + c8));
        *(u32x4*)&sA[r * LDA + c8] = v;
    }
    __syncthreads();

    int lane = t & 63, wid = t >> 6;
    int rl = lane & 15, g = lane >> 4;
    int wr = wid >> 1, wc = wid & 1;

    f32x4 acc[4][4];
#pragma unroll
    for (int i = 0; i < 4; ++i)
#pragma unroll
        for (int j = 0; j < 4; ++j) acc[i][j] = (f32x4){0.f, 0.f, 0.f, 0.f};

#pragma unroll
    for (int ks = 0; ks < 4; ++ks) {
        int koff = ks * 32 + g * 8;
        bf16x8 a[4], b[4];
#pragma unroll
        for (int ni = 0; ni < 4; ++ni)
            b[ni] = *(const bf16x8*)&l1bf[(size_t)(wc * 64 + ni * 16 + rl) * 128 + koff];
#pragma unroll
        for (int mi = 0; mi < 4; ++mi)
            a[mi] = *(const bf16x8*)&sA[(wr * 64 + mi * 16 + rl) * LDA + koff];
#pragma unroll
        for (int mi = 0; mi < 4; ++mi)
#pragma unroll
            for (int ni = 0; ni < 4; ++ni)
                acc[mi][ni] = __builtin_amdgcn_mfma_f32_16x16x32_bf16(a[mi], b[ni], acc[mi][ni], 0, 0, 0);
    }

    __syncthreads();   // all waves done reading sA -> safe to overwrite with z^T

    float bn[4];
#pragma unroll
    for (int ni = 0; ni < 4; ++ni) bn[ni] = sbias[wc * 64 + ni * 16 + rl];
#pragma unroll
    for (int mi = 0; mi < 4; ++mi) {
        int rowl = wr * 64 + mi * 16 + g * 4;
#pragma unroll
        for (int j = 0; j < 4; ++j) {
#pragma unroll
            for (int ni = 0; ni < 4; ++ni) {
                int ocol = wc * 64 + ni * 16 + rl;
                float o = fmaxf(acc[mi][ni][j] + bn[ni], 0.f);
                sA[ocol * LDA + rowl + j] = f2b(o);   // z^T: [col][row]
            }
        }
    }
    __syncthreads();

    int row = t & 127, ch = t >> 7;
    float acc2[5] = {0.f, 0.f, 0.f, 0.f, 0.f};
    const float* w2p = &w2s[ch * 5 * 128];
#pragma unroll 4
    for (int k = 0; k < 128; ++k) {
        float v = b2f(sA[k * LDA + row]);
#pragma unroll
        for (int c = 0; c < 5; ++c)
            acc2[c] = fmaf(v, w2p[c * 128 + k], acc2[c]);
    }
    int rr = r0 + row;
    if (rr < N_NODES) {
#pragma unroll
        for (int c = 0; c < 5; ++c) {
            float z = acc2[c] + b2s[ch * 5 + c];
            out[(size_t)rr * NCLASS + ch * 5 + c] = 1.f / (1.f + expf(-z));
        }
    }
}

// ================= launcher =================
extern "C" void kernel_launch(void* const* d_in, const int* in_sizes, int n_in,
                              void* d_out, int out_size, void* d_ws, size_t ws_size,
                              hipStream_t stream) {
    const float* x     = (const float*)d_in[0];
    const int*   ei    = (const int*)d_in[1];
    const float* W1    = (const float*)d_in[2];
    const float* b1    = (const float*)d_in[3];
    const float* gamma = (const float*)d_in[4];
    const float* beta  = (const float*)d_in[5];
    const float* W2    = (const float*)d_in[6];
    const float* b2    = (const float*)d_in[7];
    const float* l1W   = (const float*)d_in[8];
    const float* l1b   = (const float*)d_in[9];
    const float* l2W   = (const float*)d_in[10];
    const float* l2b   = (const float*)d_in[11];
    float* out = (float*)d_out;

    char* w = (char*)d_ws;
    ushort* hbf    = (ushort*)(w);                   // 25,600,000 B
    ushort* zbf    = (ushort*)(w + 25600000);        // 25,600,000 B
    ushort* aggout = (ushort*)(w + 51200000);        // 25,600,000 B
    int*   row_ptr = (int*)   (w + 76800000);        // 400,004 B (reserve 400,640)
    int*   csr     = (int*)   (w + 77200640);        // 6,400,000 B
    uint*  tmp     = (uint*)  (w + 83600640);        // 6,400,000 B
    int*   hist    = (int*)   (w + 90000640);        // 800,768 (reserve 801,280)
    int*   psums   = (int*)   (w + 90801920);        // reserve 4,096
    float* gsum    = (float*) (w + 90806016);        // 512 floats (2048 B)
    float* gsq     = gsum + 128;
    float* scale   = gsum + 256;
    float* shift   = gsum + 384;
    ushort* wbf    = (ushort*)(w + 90808064);        // 114,688 ushorts = 229,376 B
    ushort* w1bf   = wbf;                            // [3][128][128]
    ushort* w2bf   = wbf + 49152;                    // [3][128][128]
    ushort* l1bf   = wbf + 98304;                    // [128][128]

    const int* src = ei;
    const int* dst = ei + N_EDGES;

    const int GEMM_NB = (N_NODES + 127) / 128;       // 782

    (void)hipMemsetAsync(gsum, 0, 256 * sizeof(float), stream);

    // ---- CSR build (radix partition, zero global atomics) ----
    k_hist<<<NBLK, 256, 0, stream>>>(dst, hist);
    k_scan1<<<SCAN_BLKS, 256, 0, stream>>>(hist, psums);
    k_scan2<<<1, 1024, 0, stream>>>(psums);
    k_partition<<<NBLK, 256, 0, stream>>>(src, dst, hist, psums, tmp);
    k_bucket_fill<<<NBUK, 256, 0, stream>>>(tmp, psums, row_ptr, csr);

    // ---- x + weights -> bf16 ----
    const int CONV_NB = (N_NODES * D / 4 + 28672 + 255) / 256;
    k_conv<<<CONV_NB, 256, 0, stream>>>(x, W1, W2, l1W, hbf, wbf);

    // ---- 3 GIN layers ----
    for (int l = 0; l < NLAYERS; ++l) {
        k_aggregate<<<N_NODES / 4, 256, 0, stream>>>(hbf, row_ptr, csr, aggout);
        // z = (h+agg) @ W1.T + b1  (bf16 out) + fused column stats
        k_gemm<0, 0, 1><<<GEMM_NB, 256, 0, stream>>>(aggout, w1bf + l * D * D, b1 + l * D,
                                                     nullptr, nullptr, zbf, gsum, gsq, N_NODES);
        k_bnfin<<<1, 128, 0, stream>>>(gsum, gsq, gamma + l * D, beta + l * D, scale, shift);
        // h' = relu( relu(BN(z)) @ W2.T + b2 )
        k_gemm<2, 1, 0><<<GEMM_NB, 256, 0, stream>>>(zbf, w2bf + l * D * D, b2 + l * D,
                                                     scale, shift, hbf, nullptr, nullptr, N_NODES);
    }

    // ---- fused head ----
    k_head<<<GEMM_NB, 256, 0, stream>>>(hbf, l1bf, l1b, l2W, l2b, out);
}